// Round 14
// baseline (315.510 us; speedup 1.0000x reference)
//
#include <hip/hip_runtime.h>
#include <math.h>

#define N_   8
#define C_   64
#define H_   128
#define W_   128
#define HW_  (H_ * W_)
#define CHW_ (C_ * HW_)
#define K_   3
#define CO_BLK  8
#define N_CG    (C_ / CO_BLK)   // 8 co-groups
#define TILE_H 16               // 8 row-threads x 2 px
#define TILE_W 32               // 16 col-threads x 2 px
#define WROW 12                 // padded weight row (9 used) -> 16B-aligned
#define WCHUNK 32               // ci per weight-stage chunk (2 chunks total)
#define WSTRIDE (C_ * K_ * K_)  // 576 floats between consecutive co's
#define BN_EPS 1e-5
#define POW_EPS 1e-12f

// One |x-w| accumulate in EXACTLY 2 VALU instructions (VGPR operands).
#define MAC_TERM(accv, wv, xvk) do { float t_;                         \
    asm("v_sub_f32 %1, %2, %3\n\t"                                     \
        "v_add_f32 %0, %0, |%1|"                                       \
        : "+v"(accv), "=&v"(t_)                                        \
        : "v"(wv), "v"(xvk));                                          \
  } while (0)

// R12 post-mortem: grid supplies only 16 waves/CU (50% cap) and the 32
// barrier-pairs + x ds_write staging still idle ~40% of SIMD time. This
// version removes x from LDS entirely: the 4x4 window per ci is read
// straight from global (L1/L2-resident; 16 clamped loads + mask-mul ~ 4%
// of MAC issue), borders via precomputed clamp+0/1 mask. Weights stay in
// LDS (2 chunks of 32 ci -> only 4 barriers TOTAL), read as uniform-addr
// broadcasts. With no per-chunk barriers the compiler freely hoists ci+1's
// VMEM loads under ci's 1152-cyc MAC burst (counted vmcnt at last).
__global__ __launch_bounds__(128, 4) void adder_kernel(
    const float* __restrict__ x, const float* __restrict__ weight,
    float* __restrict__ y, double* __restrict__ sums)
{
    __shared__ __align__(16) float wl[WCHUNK * CO_BLK * WROW];  // 12288 B
    __shared__ float red[CO_BLK][2][2];                         // stat partials

    const int tx = threadIdx.x & 15;        // col-pair 0..15
    const int ty = threadIdx.x >> 4;        // row-pair 0..7
    const int tile_h = blockIdx.x >> 2;     // 8 tiles of 16 rows
    const int tile_w = blockIdx.x & 3;      // 4 tiles of 32 cols
    const int n   = blockIdx.y;
    const int co0 = blockIdx.z * CO_BLK;
    const int h0 = tile_h * TILE_H;
    const int w0 = tile_w * TILE_W;

    float a00[CO_BLK], a01[CO_BLK], a10[CO_BLK], a11[CO_BLK];
#pragma unroll
    for (int j = 0; j < CO_BLK; ++j) { a00[j]=0.f; a01[j]=0.f; a10[j]=0.f; a11[j]=0.f; }

    const float* xn = x + n * CHW_;

    // Precompute clamped in-plane offsets + 0/1 masks for the 4x4 window.
    // Load from clamped (always-valid) address, multiply by mask -> zero-pad.
    int   off16[16];
    float msk16[16];
#pragma unroll
    for (int r = 0; r < 4; ++r) {
#pragma unroll
        for (int c = 0; c < 4; ++c) {
            int gh = h0 + 2 * ty - 1 + r;
            int gw = w0 + 2 * tx - 1 + c;
            bool ok = ((unsigned)gh < (unsigned)H_) && ((unsigned)gw < (unsigned)W_);
            int ch = gh < 0 ? 0 : (gh > H_ - 1 ? H_ - 1 : gh);
            int cw = gw < 0 ? 0 : (gw > W_ - 1 ? W_ - 1 : gw);
            off16[r * 4 + c] = ch * W_ + cw;
            msk16[r * 4 + c] = ok ? 1.f : 0.f;
        }
    }

    for (int half = 0; half < 2; ++half) {
        const int cb0 = half * WCHUNK;
        __syncthreads();   // protect previous chunk's weight reads
        // Stage 32ci x 8co x 9 weights -> wl[ci][co][12] (16B-aligned rows).
        for (int idx = threadIdx.x; idx < WCHUNK * CO_BLK * 9; idx += 128) {
            int ci = idx / (CO_BLK * 9);
            int r  = idx - ci * (CO_BLK * 9);
            int co = r / 9;
            int k  = r - co * 9;
            wl[(ci * CO_BLK + co) * WROW + k] =
                weight[(co0 + co) * WSTRIDE + (cb0 + ci) * 9 + k];
        }
        __syncthreads();

        const float* xp = xn + cb0 * HW_;
#pragma unroll 1
        for (int ci = 0; ci < WCHUNK; ++ci) {
            // 4x4 x-window straight from global (L1/L2-hit), zero via mask.
            float xv[16];
#pragma unroll
            for (int i = 0; i < 16; ++i)
                xv[i] = xp[off16[i]] * msk16[i];

            const float* wrow = &wl[ci * CO_BLK * WROW];
#pragma unroll
            for (int j = 0; j < CO_BLK; ++j) {
                float4 wa = *(const float4*)(wrow + j * WROW);
                float4 wb = *(const float4*)(wrow + j * WROW + 4);
                float  w8 = wrow[j * WROW + 8];
                // tap (kh,kw) feeds pixel (pr,pc) from xv[(pr+kh)*4 + pc+kw]
                MAC_TERM(a00[j], wa.x, xv[0]);  MAC_TERM(a01[j], wa.x, xv[1]);
                MAC_TERM(a10[j], wa.x, xv[4]);  MAC_TERM(a11[j], wa.x, xv[5]);
                MAC_TERM(a00[j], wa.y, xv[1]);  MAC_TERM(a01[j], wa.y, xv[2]);
                MAC_TERM(a10[j], wa.y, xv[5]);  MAC_TERM(a11[j], wa.y, xv[6]);
                MAC_TERM(a00[j], wa.z, xv[2]);  MAC_TERM(a01[j], wa.z, xv[3]);
                MAC_TERM(a10[j], wa.z, xv[6]);  MAC_TERM(a11[j], wa.z, xv[7]);
                MAC_TERM(a00[j], wa.w, xv[4]);  MAC_TERM(a01[j], wa.w, xv[5]);
                MAC_TERM(a10[j], wa.w, xv[8]);  MAC_TERM(a11[j], wa.w, xv[9]);
                MAC_TERM(a00[j], wb.x, xv[5]);  MAC_TERM(a01[j], wb.x, xv[6]);
                MAC_TERM(a10[j], wb.x, xv[9]);  MAC_TERM(a11[j], wb.x, xv[10]);
                MAC_TERM(a00[j], wb.y, xv[6]);  MAC_TERM(a01[j], wb.y, xv[7]);
                MAC_TERM(a10[j], wb.y, xv[10]); MAC_TERM(a11[j], wb.y, xv[11]);
                MAC_TERM(a00[j], wb.z, xv[8]);  MAC_TERM(a01[j], wb.z, xv[9]);
                MAC_TERM(a10[j], wb.z, xv[12]); MAC_TERM(a11[j], wb.z, xv[13]);
                MAC_TERM(a00[j], wb.w, xv[9]);  MAC_TERM(a01[j], wb.w, xv[10]);
                MAC_TERM(a10[j], wb.w, xv[13]); MAC_TERM(a11[j], wb.w, xv[14]);
                MAC_TERM(a00[j], w8,   xv[10]); MAC_TERM(a01[j], w8,   xv[11]);
                MAC_TERM(a10[j], w8,   xv[14]); MAC_TERM(a11[j], w8,   xv[15]);
            }
            xp += HW_;
        }
    }

    // Epilogue: y = -acc + residual (2 rows x float2); fused sum/sumsq.
    const int r0 = h0 + 2 * ty, c0 = w0 + 2 * tx;
    float* yo = y + n * CHW_ + co0 * HW_ + r0 * W_ + c0;
    const float* xrp = xn + co0 * HW_ + r0 * W_ + c0;
    const int lane = threadIdx.x & 63;
    const int wid  = threadIdx.x >> 6;   // 0..1 (2 waves)

#pragma unroll
    for (int j = 0; j < CO_BLK; ++j) {
        float2 rv0 = *(const float2*)(xrp + j * HW_);
        float2 rv1 = *(const float2*)(xrp + j * HW_ + W_);
        float v00 = -a00[j] + rv0.x, v01 = -a01[j] + rv0.y;
        float v10 = -a10[j] + rv1.x, v11 = -a11[j] + rv1.y;
        float2 o0; o0.x = v00; o0.y = v01;
        float2 o1; o1.x = v10; o1.y = v11;
        *(float2*)(yo + j * HW_)      = o0;
        *(float2*)(yo + j * HW_ + W_) = o1;
        float s  = v00 + v01 + v10 + v11;
        float ss = v00 * v00 + v01 * v01 + v10 * v10 + v11 * v11;
#pragma unroll
        for (int off = 32; off > 0; off >>= 1) {
            s  += __shfl_down(s, off);
            ss += __shfl_down(ss, off);
        }
        if (lane == 0) { red[j][0][wid] = s; red[j][1][wid] = ss; }
    }
    __syncthreads();
    if (threadIdx.x < CO_BLK) {
        int j = threadIdx.x;
        float S  = red[j][0][0] + red[j][0][1];
        float SS = red[j][1][0] + red[j][1][1];
        atomicAdd(&sums[co0 + j], (double)S);
        atomicAdd(&sums[C_ + co0 + j], (double)SS);
    }
}

// Per-channel scale/shift from batch stats.
__global__ void finalize_kernel(const double* __restrict__ sums,
                                const float* __restrict__ gamma,
                                const float* __restrict__ beta,
                                float* __restrict__ sc)
{
    const int c = threadIdx.x;  // 64 threads
    const double cnt = (double)(N_ * HW_);
    double mean = sums[c] / cnt;
    double var  = sums[C_ + c] / cnt - mean * mean;
    float inv   = (float)(1.0 / sqrt(var + (double)BN_EPS));
    float scale = gamma[c] * inv;
    float shift = beta[c] - (float)mean * scale;
    sc[c]      = scale;
    sc[C_ + c] = shift;
}

// In-place BN affine + power activation, float4 vectorized.
// alpha==1 fast path: sign(t)*(|t|+1e-12)^1 = t +- 1e-12 (below tolerance).
__global__ __launch_bounds__(256) void apply_kernel(
    float* __restrict__ y, const float* __restrict__ sc,
    const float* __restrict__ alpha_p)
{
    const int idx = blockIdx.x * 256 + threadIdx.x;   // float4 index
    const float alpha = alpha_p[0];
    const int e0 = idx * 4;
    const int c = (e0 / HW_) & (C_ - 1);   // HW_ divisible by 4: all 4 in same channel
    const float scale = sc[c];
    const float shift = sc[C_ + c];

    float4 v = reinterpret_cast<float4*>(y)[idx];
    float* pv = reinterpret_cast<float*>(&v);
    if (alpha == 1.0f) {
#pragma unroll
        for (int i = 0; i < 4; ++i)
            pv[i] = pv[i] * scale + shift;
    } else {
#pragma unroll
        for (int i = 0; i < 4; ++i) {
            float t = pv[i] * scale + shift;
            float sgn = (t > 0.f) ? 1.f : ((t < 0.f) ? -1.f : 0.f);
            pv[i] = sgn * powf(fabsf(t) + POW_EPS, alpha);
        }
    }
    reinterpret_cast<float4*>(y)[idx] = v;
}

extern "C" void kernel_launch(void* const* d_in, const int* in_sizes, int n_in,
                              void* d_out, int out_size, void* d_ws, size_t ws_size,
                              hipStream_t stream)
{
    const float* x      = (const float*)d_in[0];
    const float* weight = (const float*)d_in[1];
    const float* gamma  = (const float*)d_in[2];
    const float* beta   = (const float*)d_in[3];
    const float* alpha  = (const float*)d_in[4];
    float* out = (float*)d_out;

    double* sums = (double*)d_ws;                                // 128 doubles
    float*  sc   = (float*)((char*)d_ws + 128 * sizeof(double)); // 128 floats

    hipMemsetAsync(d_ws, 0, 128 * sizeof(double), stream);

    adder_kernel<<<dim3(32, N_, N_CG), 128, 0, stream>>>(x, weight, out, sums);
    finalize_kernel<<<1, C_, 0, stream>>>(sums, gamma, beta, sc);

    const int n4 = (N_ * CHW_) / 4;           // 2,097,152 float4s
    apply_kernel<<<n4 / 256, 256, 0, stream>>>(out, sc, alpha);
}

// Round 15
// 290.270 us; speedup vs baseline: 1.0870x; 1.0870x over previous
//
#include <hip/hip_runtime.h>
#include <math.h>

#define N_   8
#define C_   64
#define H_   128
#define W_   128
#define HW_  (H_ * W_)
#define CHW_ (C_ * HW_)
#define K_   3
#define CI2  2                  // ci per chunk (double-buffered)
#define CO_BLK  8
#define N_CG    (C_ / CO_BLK)   // 8 co-groups
#define TILE_H 16               // 8 row-threads x 2 px
#define TILE_W 32               // 16 col-threads x 2 px
#define HALO_H (TILE_H + 2)      // 18
#define HALO_W (TILE_W + 2)      // 34
#define XSTR   36                // b64-aligned row stride
#define CISZ   (HALO_H * XSTR)   // 648 floats per ci plane
#define PLANE  (HALO_H * HALO_W) // 612 staged elems per ci plane
#define NSLOT  5                 // ceil(612/128)
#define WROW 12                  // padded weight row (9 used) -> 16B-aligned
#define WCI  (CO_BLK * WROW)     // 96 floats per ci
#define WSTRIDE (C_ * K_ * K_)   // 576 floats between consecutive co's
#define BN_EPS 1e-5
#define POW_EPS 1e-12f

// One |x-w| accumulate in EXACTLY 2 VALU instructions (VGPR operands).
#define MAC_TERM(accv, wv, xvk) do { float t_;                         \
    asm("v_sub_f32 %1, %2, %3\n\t"                                     \
        "v_add_f32 %0, %0, |%1|"                                       \
        : "+v"(accv), "=&v"(t_)                                        \
        : "v"(wv), "v"(xvk));                                          \
  } while (0)

// R14 post-mortem: x-from-global regressed (277 vs R12's 232) -- 16 scalar
// VMEM loads/ci serialize behind vmcnt and don't pipeline. Reverted to R12
// (x+w in LDS, T14 reg-staging). R12's residual: VALU issue ~= floor, but
// its 2-barriers-per-chunk expose the whole ds_write phase. This version
// DOUBLE-BUFFERS the LDS (CI2=2 -> 12 KB, still 8 blocks/CU): per chunk,
// issue next loads (fly under MAC), MAC buf[cur], write buf[cur^1], ONE
// barrier. Writes overlap other waves' MACs; only the join is exposed.
__global__ __launch_bounds__(128, 4) void adder_kernel(
    const float* __restrict__ x, const float* __restrict__ weight,
    float* __restrict__ y, double* __restrict__ sums)
{
    __shared__ __align__(16) float sx[2][CI2 * CISZ];   // 10368 B
    __shared__ __align__(16) float wl[2][CI2 * WCI];    //  1536 B
    __shared__ float red[CO_BLK][2][2];                 // stat partials

    const int tx = threadIdx.x & 15;        // col-pair 0..15
    const int ty = threadIdx.x >> 4;        // row-pair 0..7
    const int tile_h = blockIdx.x >> 2;     // 8 tiles of 16 rows
    const int tile_w = blockIdx.x & 3;      // 4 tiles of 32 cols
    const int n   = blockIdx.y;
    const int co0 = blockIdx.z * CO_BLK;
    const int h0 = tile_h * TILE_H;
    const int w0 = tile_w * TILE_W;

    float a00[CO_BLK], a01[CO_BLK], a10[CO_BLK], a11[CO_BLK];
#pragma unroll
    for (int j = 0; j < CO_BLK; ++j) { a00[j]=0.f; a01[j]=0.f; a10[j]=0.f; a11[j]=0.f; }

    const float* xn = x + n * CHW_;

    // One-time affine staging offsets (5 slots x 128 threads cover 612 elems).
    int lx[NSLOT], gx[NSLOT];
#pragma unroll
    for (int s = 0; s < NSLOT; ++s) {
        int idx = threadIdx.x + s * 128;
        if (idx < PLANE) {
            int r = idx / HALO_W, c = idx - r * HALO_W;
            int gh = h0 + r - 1, gw = w0 + c - 1;
            lx[s] = r * XSTR + c;
            gx[s] = ((unsigned)gh < (unsigned)H_ && (unsigned)gw < (unsigned)W_)
                    ? (gh * W_ + gw) : -1;
        } else { lx[s] = -1; gx[s] = -1; }
    }
    // Weight ownership: 2ci x 8co x 9 = 144 slots; thread t owns slot t and
    // (t<16) slot t+128. LDS offset + cb-affine global offset per slot.
    int wlo0, wgo0, wlo1 = -1, wgo1 = 0;
    {
        int i0 = threadIdx.x;                 // always < 144
        int ci = i0 / (CO_BLK * 9), r = i0 - ci * (CO_BLK * 9);
        int co = r / 9, k = r - co * 9;
        wlo0 = (ci * CO_BLK + co) * WROW + k;
        wgo0 = (co0 + co) * WSTRIDE + ci * 9 + k;
        int i1 = threadIdx.x + 128;
        if (i1 < CI2 * CO_BLK * 9) {
            ci = i1 / (CO_BLK * 9); r = i1 - ci * (CO_BLK * 9);
            co = r / 9; k = r - co * 9;
            wlo1 = (ci * CO_BLK + co) * WROW + k;
            wgo1 = (co0 + co) * WSTRIDE + ci * 9 + k;
        }
    }

    // Register staging (statically indexed -> VGPRs).
    float rs[CI2 * NSLOT];   // 10
    float rwA, rwB;

#define ISSUE_STAGE(CBN) do {                                            \
        const float* xp_ = xn + (CBN) * HW_;                             \
        _Pragma("unroll")                                                \
        for (int ci_ = 0; ci_ < CI2; ++ci_)                              \
            _Pragma("unroll")                                            \
            for (int s_ = 0; s_ < NSLOT; ++s_)                           \
                rs[ci_ * NSLOT + s_] = (gx[s_] >= 0)                     \
                    ? xp_[ci_ * HW_ + gx[s_]] : 0.f;                     \
        rwA = weight[wgo0 + (CBN) * 9];                                  \
        if (wlo1 >= 0) rwB = weight[wgo1 + (CBN) * 9];                   \
    } while (0)

#define WRITE_STAGE(BUF) do {                                            \
        _Pragma("unroll")                                                \
        for (int ci_ = 0; ci_ < CI2; ++ci_)                              \
            _Pragma("unroll")                                            \
            for (int s_ = 0; s_ < NSLOT; ++s_)                           \
                if (lx[s_] >= 0)                                         \
                    sx[BUF][ci_ * CISZ + lx[s_]] = rs[ci_ * NSLOT + s_]; \
        wl[BUF][wlo0] = rwA;                                             \
        if (wlo1 >= 0) wl[BUF][wlo1] = rwB;                              \
    } while (0)

    // Prologue: fill buffer 0.
    ISSUE_STAGE(0);
    WRITE_STAGE(0);
    __syncthreads();

    int cur = 0;
    for (int cb = 0; cb < C_; cb += CI2) {
        const bool more = (cb + CI2 < C_);
        if (more) ISSUE_STAGE(cb + CI2);   // VMEM flies under the MAC burst

#pragma unroll 1
        for (int ci = 0; ci < CI2; ++ci) {
            const float* sxc = &sx[cur][ci * CISZ];
            // 4x4 window serves the 2x2 pixel quad: 8x ds_read_b64.
            float xv[4][4];
#pragma unroll
            for (int r = 0; r < 4; ++r) {
                float2 a = *(const float2*)(sxc + (2 * ty + r) * XSTR + 2 * tx);
                float2 b = *(const float2*)(sxc + (2 * ty + r) * XSTR + 2 * tx + 2);
                xv[r][0] = a.x; xv[r][1] = a.y; xv[r][2] = b.x; xv[r][3] = b.y;
            }

            const float* wrow = &wl[cur][ci * WCI];
#pragma unroll
            for (int j = 0; j < CO_BLK; ++j) {
                float4 wa = *(const float4*)(wrow + j * WROW);
                float4 wb = *(const float4*)(wrow + j * WROW + 4);
                float  w8 = wrow[j * WROW + 8];
                // tap (kh,kw) feeds pixel (pr,pc) from xv[pr+kh][pc+kw]
                MAC_TERM(a00[j], wa.x, xv[0][0]); MAC_TERM(a01[j], wa.x, xv[0][1]);
                MAC_TERM(a10[j], wa.x, xv[1][0]); MAC_TERM(a11[j], wa.x, xv[1][1]);
                MAC_TERM(a00[j], wa.y, xv[0][1]); MAC_TERM(a01[j], wa.y, xv[0][2]);
                MAC_TERM(a10[j], wa.y, xv[1][1]); MAC_TERM(a11[j], wa.y, xv[1][2]);
                MAC_TERM(a00[j], wa.z, xv[0][2]); MAC_TERM(a01[j], wa.z, xv[0][3]);
                MAC_TERM(a10[j], wa.z, xv[1][2]); MAC_TERM(a11[j], wa.z, xv[1][3]);
                MAC_TERM(a00[j], wa.w, xv[1][0]); MAC_TERM(a01[j], wa.w, xv[1][1]);
                MAC_TERM(a10[j], wa.w, xv[2][0]); MAC_TERM(a11[j], wa.w, xv[2][1]);
                MAC_TERM(a00[j], wb.x, xv[1][1]); MAC_TERM(a01[j], wb.x, xv[1][2]);
                MAC_TERM(a10[j], wb.x, xv[2][1]); MAC_TERM(a11[j], wb.x, xv[2][2]);
                MAC_TERM(a00[j], wb.y, xv[1][2]); MAC_TERM(a01[j], wb.y, xv[1][3]);
                MAC_TERM(a10[j], wb.y, xv[2][2]); MAC_TERM(a11[j], wb.y, xv[2][3]);
                MAC_TERM(a00[j], wb.z, xv[2][0]); MAC_TERM(a01[j], wb.z, xv[2][1]);
                MAC_TERM(a10[j], wb.z, xv[3][0]); MAC_TERM(a11[j], wb.z, xv[3][1]);
                MAC_TERM(a00[j], wb.w, xv[2][1]); MAC_TERM(a01[j], wb.w, xv[2][2]);
                MAC_TERM(a10[j], wb.w, xv[3][1]); MAC_TERM(a11[j], wb.w, xv[3][2]);
                MAC_TERM(a00[j], w8,   xv[2][2]); MAC_TERM(a01[j], w8,   xv[2][3]);
                MAC_TERM(a10[j], w8,   xv[3][2]); MAC_TERM(a11[j], w8,   xv[3][3]);
            }
        }

        if (more) {
            WRITE_STAGE(cur ^ 1);   // fill idle buffer; overlaps others' MACs
            __syncthreads();        // single barrier per chunk
            cur ^= 1;
        }
    }

    // Epilogue: y = -acc + residual (2 rows x float2); fused sum/sumsq.
    const int r0 = h0 + 2 * ty, c0 = w0 + 2 * tx;
    float* yo = y + n * CHW_ + co0 * HW_ + r0 * W_ + c0;
    const float* xrp = xn + co0 * HW_ + r0 * W_ + c0;
    const int lane = threadIdx.x & 63;
    const int wid  = threadIdx.x >> 6;   // 0..1 (2 waves)

#pragma unroll
    for (int j = 0; j < CO_BLK; ++j) {
        float2 rv0 = *(const float2*)(xrp + j * HW_);
        float2 rv1 = *(const float2*)(xrp + j * HW_ + W_);
        float v00 = -a00[j] + rv0.x, v01 = -a01[j] + rv0.y;
        float v10 = -a10[j] + rv1.x, v11 = -a11[j] + rv1.y;
        float2 o0; o0.x = v00; o0.y = v01;
        float2 o1; o1.x = v10; o1.y = v11;
        *(float2*)(yo + j * HW_)      = o0;
        *(float2*)(yo + j * HW_ + W_) = o1;
        float s  = v00 + v01 + v10 + v11;
        float ss = v00 * v00 + v01 * v01 + v10 * v10 + v11 * v11;
#pragma unroll
        for (int off = 32; off > 0; off >>= 1) {
            s  += __shfl_down(s, off);
            ss += __shfl_down(ss, off);
        }
        if (lane == 0) { red[j][0][wid] = s; red[j][1][wid] = ss; }
    }
    __syncthreads();
    if (threadIdx.x < CO_BLK) {
        int j = threadIdx.x;
        float S  = red[j][0][0] + red[j][0][1];
        float SS = red[j][1][0] + red[j][1][1];
        atomicAdd(&sums[co0 + j], (double)S);
        atomicAdd(&sums[C_ + co0 + j], (double)SS);
    }
}

// Per-channel scale/shift from batch stats.
__global__ void finalize_kernel(const double* __restrict__ sums,
                                const float* __restrict__ gamma,
                                const float* __restrict__ beta,
                                float* __restrict__ sc)
{
    const int c = threadIdx.x;  // 64 threads
    const double cnt = (double)(N_ * HW_);
    double mean = sums[c] / cnt;
    double var  = sums[C_ + c] / cnt - mean * mean;
    float inv   = (float)(1.0 / sqrt(var + (double)BN_EPS));
    float scale = gamma[c] * inv;
    float shift = beta[c] - (float)mean * scale;
    sc[c]      = scale;
    sc[C_ + c] = shift;
}

// In-place BN affine + power activation, float4 vectorized.
// alpha==1 fast path: sign(t)*(|t|+1e-12)^1 = t +- 1e-12 (below tolerance).
__global__ __launch_bounds__(256) void apply_kernel(
    float* __restrict__ y, const float* __restrict__ sc,
    const float* __restrict__ alpha_p)
{
    const int idx = blockIdx.x * 256 + threadIdx.x;   // float4 index
    const float alpha = alpha_p[0];
    const int e0 = idx * 4;
    const int c = (e0 / HW_) & (C_ - 1);   // HW_ divisible by 4: all 4 in same channel
    const float scale = sc[c];
    const float shift = sc[C_ + c];

    float4 v = reinterpret_cast<float4*>(y)[idx];
    float* pv = reinterpret_cast<float*>(&v);
    if (alpha == 1.0f) {
#pragma unroll
        for (int i = 0; i < 4; ++i)
            pv[i] = pv[i] * scale + shift;
    } else {
#pragma unroll
        for (int i = 0; i < 4; ++i) {
            float t = pv[i] * scale + shift;
            float sgn = (t > 0.f) ? 1.f : ((t < 0.f) ? -1.f : 0.f);
            pv[i] = sgn * powf(fabsf(t) + POW_EPS, alpha);
        }
    }
    reinterpret_cast<float4*>(y)[idx] = v;
}

extern "C" void kernel_launch(void* const* d_in, const int* in_sizes, int n_in,
                              void* d_out, int out_size, void* d_ws, size_t ws_size,
                              hipStream_t stream)
{
    const float* x      = (const float*)d_in[0];
    const float* weight = (const float*)d_in[1];
    const float* gamma  = (const float*)d_in[2];
    const float* beta   = (const float*)d_in[3];
    const float* alpha  = (const float*)d_in[4];
    float* out = (float*)d_out;

    double* sums = (double*)d_ws;                                // 128 doubles
    float*  sc   = (float*)((char*)d_ws + 128 * sizeof(double)); // 128 floats

    hipMemsetAsync(d_ws, 0, 128 * sizeof(double), stream);

    adder_kernel<<<dim3(32, N_, N_CG), 128, 0, stream>>>(x, weight, out, sums);
    finalize_kernel<<<1, C_, 0, stream>>>(sums, gamma, beta, sc);

    const int n4 = (N_ * CHW_) / 4;           // 2,097,152 float4s
    apply_kernel<<<n4 / 256, 256, 0, stream>>>(out, sc, alpha);
}